// Round 6
// baseline (143.252 us; speedup 1.0000x reference)
//
#include <hip/hip_runtime.h>

#define NN 768
#define FD 256
#define HD 128

__device__ __forceinline__ float relu(float x) { return x > 0.f ? x : 0.f; }

__device__ __forceinline__ float rdot(float4 a, float4 b, float4 w) {
    float s = relu(a.x + b.x) * w.x;
    s = fmaf(relu(a.y + b.y), w.y, s);
    s = fmaf(relu(a.z + b.z), w.z, s);
    s = fmaf(relu(a.w + b.w), w.w, s);
    return s;
}

// K1: blocks 0..255 (768 thr): rows 3b..3b+2 -> dinv[i], t1D[i,k]=dinv[i]*(x@w1)[i,k]
//     block 256: c[k] = temb[t]@we1[2H:] + be1
__global__ __launch_bounds__(768) void k_prep(
        const float* __restrict__ x, const float* __restrict__ adj,
        const float* __restrict__ w1, const float* __restrict__ temb,
        const float* __restrict__ we1, const float* __restrict__ be1,
        const int* __restrict__ tptr, float* __restrict__ dinv,
        float* __restrict__ cvec, float* __restrict__ t1D) {
    int b = blockIdx.x, tid = threadIdx.x;
    if (b == 256) {
        __shared__ float ts[HD];
        if (tid < HD) ts[tid] = temb[tptr[0] * HD + tid];
        __syncthreads();
        if (tid < HD) {
            float a0 = be1[tid], a1 = 0.f, a2 = 0.f, a3 = 0.f;
            for (int m = 0; m < HD; m += 4) {
                a0 = fmaf(ts[m + 0], we1[(2 * HD + m + 0) * HD + tid], a0);
                a1 = fmaf(ts[m + 1], we1[(2 * HD + m + 1) * HD + tid], a1);
                a2 = fmaf(ts[m + 2], we1[(2 * HD + m + 2) * HD + tid], a2);
                a3 = fmaf(ts[m + 3], we1[(2 * HD + m + 3) * HD + tid], a3);
            }
            cvec[tid] = (a0 + a1) + (a2 + a3);
        }
        return;
    }
    int i0 = b * 3;
    __shared__ float xs[3][FD];
    __shared__ float part[3][2][HD];
    __shared__ float red[12];
    __shared__ float sdi[3];
    if (tid < 192) {  // stage 3 x-rows as float4
        int row = tid >> 6, m4 = tid & 63;
        *(float4*)&xs[row][m4 * 4] = *(const float4*)&x[(i0 + row) * FD + m4 * 4];
    }
    {   // dinv: 256 threads per row, one float4 each (192 active)
        int r2 = tid >> 8, s = tid & 255;
        float sum = 0.f;
        if (s < 192) {
            float4 a = *(const float4*)&adj[(i0 + r2) * NN + s * 4];
            sum = (a.x + a.y) + (a.z + a.w);
        }
#pragma unroll
        for (int off = 32; off > 0; off >>= 1) sum += __shfl_down(sum, off, 64);
        if ((tid & 63) == 0) red[tid >> 6] = sum;
    }
    __syncthreads();
    if (tid < 3) {
        float t = (red[4 * tid] + red[4 * tid + 1]) + (red[4 * tid + 2] + red[4 * tid + 3]);
        float d = rsqrtf(t + 1.f);
        sdi[tid] = d; dinv[i0 + tid] = d;
    }
    __syncthreads();
    int r = tid >> 8, half = (tid >> 7) & 1, k = tid & 127;
    float a0 = 0.f, a1 = 0.f, a2 = 0.f, a3 = 0.f;
    for (int g = 128 * half; g < 128 * half + 128; g += 16) {
        float wv[16];
#pragma unroll
        for (int u = 0; u < 16; ++u) wv[u] = w1[(g + u) * HD + k];
#pragma unroll
        for (int u = 0; u < 16; ++u) {
            float xv = xs[r][g + u];
            if ((u & 3) == 0) a0 = fmaf(xv, wv[u], a0);
            else if ((u & 3) == 1) a1 = fmaf(xv, wv[u], a1);
            else if ((u & 3) == 2) a2 = fmaf(xv, wv[u], a2);
            else a3 = fmaf(xv, wv[u], a3);
        }
    }
    part[r][half][k] = (a0 + a1) + (a2 + a3);
    __syncthreads();
    if (half == 0) t1D[(i0 + r) * HD + k] = sdi[r] * (part[r][0][k] + part[r][1][k]);
}

// Partial aggregation over 384 j's: sum_j arow[j]*tin[j*HD+k]
__device__ __forceinline__ float agg_half(const float* __restrict__ arow,
                                          const float* __restrict__ tbase, int k) {
    float a0 = 0.f, a1 = 0.f, a2 = 0.f, a3 = 0.f;
    for (int g = 0; g < 384; g += 32) {
        float4 av[8];
        float tv[8][4];
#pragma unroll
        for (int u = 0; u < 8; ++u) av[u] = *(const float4*)&arow[g + u * 4];
#pragma unroll
        for (int u = 0; u < 8; ++u) {
#pragma unroll
            for (int c = 0; c < 4; ++c) tv[u][c] = tbase[(g + u * 4 + c) * HD + k];
        }
#pragma unroll
        for (int u = 0; u < 8; ++u) {
            a0 = fmaf(av[u].x, tv[u][0], a0);
            a1 = fmaf(av[u].y, tv[u][1], a1);
            a2 = fmaf(av[u].z, tv[u][2], a2);
            a3 = fmaf(av[u].w, tv[u][3], a3);
        }
    }
    return (a0 + a1) + (a2 + a3);
}

// K2: 256 blocks × 768 thr: rows 3b..3b+2: h1=relu(dinv*(agg+tinD[i])); outD=dinv*(h1@w2)
__global__ __launch_bounds__(768) void k_gcn_w(
        const float* __restrict__ adj, const float* __restrict__ dinv,
        const float* __restrict__ tin, const float* __restrict__ w2,
        float* __restrict__ outD) {
    int b = blockIdx.x, tid = threadIdx.x;
    int r = tid >> 8, half = (tid >> 7) & 1, k = tid & 127;
    int i = b * 3 + r;
    __shared__ float part[3][2][HD];
    __shared__ float gs[3][HD];
    part[r][half][k] = agg_half(adj + i * NN + 384 * half, tin + 384 * half * HD, k);
    __syncthreads();
    if (half == 0) {
        float acc = part[r][0][k] + part[r][1][k] + tin[i * HD + k];
        gs[r][k] = relu(dinv[i] * acc);
    }
    __syncthreads();
    float a0 = 0.f, a1 = 0.f, a2 = 0.f, a3 = 0.f;
    for (int g = 64 * half; g < 64 * half + 64; g += 16) {
        float wv[16];
#pragma unroll
        for (int u = 0; u < 16; ++u) wv[u] = w2[(g + u) * HD + k];
#pragma unroll
        for (int u = 0; u < 16; ++u) {
            float hv = gs[r][g + u];
            if ((u & 3) == 0) a0 = fmaf(hv, wv[u], a0);
            else if ((u & 3) == 1) a1 = fmaf(hv, wv[u], a1);
            else if ((u & 3) == 2) a2 = fmaf(hv, wv[u], a2);
            else a3 = fmaf(hv, wv[u], a3);
        }
    }
    part[r][half][k] = (a0 + a1) + (a2 + a3);
    __syncthreads();
    if (half == 0) outD[i * HD + k] = dinv[i] * (part[r][0][k] + part[r][1][k]);
}

// K3: like K2 but epilogue -> p = h2@we1[:H]+c, q = h2@we1[H:2H]
__global__ __launch_bounds__(768) void k_gcn_pq(
        const float* __restrict__ adj, const float* __restrict__ dinv,
        const float* __restrict__ tin, const float* __restrict__ we1,
        const float* __restrict__ cvec, float* __restrict__ p, float* __restrict__ q) {
    int b = blockIdx.x, tid = threadIdx.x;
    int r = tid >> 8, half = (tid >> 7) & 1, k = tid & 127;
    int i = b * 3 + r;
    __shared__ float partp[3][2][HD];
    __shared__ float partq[3][2][HD];
    __shared__ float gs[3][HD];
    partp[r][half][k] = agg_half(adj + i * NN + 384 * half, tin + 384 * half * HD, k);
    __syncthreads();
    if (half == 0) {
        float acc = partp[r][0][k] + partp[r][1][k] + tin[i * HD + k];
        gs[r][k] = relu(dinv[i] * acc);
    }
    __syncthreads();
    float p0 = 0.f, p1 = 0.f, q0 = 0.f, q1 = 0.f;
    for (int g = 64 * half; g < 64 * half + 64; g += 8) {
        float wp[8], wq[8];
#pragma unroll
        for (int u = 0; u < 8; ++u) {
            wp[u] = we1[(g + u) * HD + k];
            wq[u] = we1[(HD + g + u) * HD + k];
        }
#pragma unroll
        for (int u = 0; u < 8; ++u) {
            float hv = gs[r][g + u];
            if (u & 1) { p1 = fmaf(hv, wp[u], p1); q1 = fmaf(hv, wq[u], q1); }
            else       { p0 = fmaf(hv, wp[u], p0); q0 = fmaf(hv, wq[u], q0); }
        }
    }
    partp[r][half][k] = p0 + p1;
    partq[r][half][k] = q0 + q1;
    __syncthreads();
    if (half == 0) {
        p[i * HD + k] = cvec[k] + partp[r][0][k] + partp[r][1][k];
        q[i * HD + k] = partq[r][0][k] + partq[r][1][k];
    }
}

// K4: 16x16 tile pairs (bi<=bj over 48 tiles -> 1176 blocks), 64 threads, 2x2 per thread.
__global__ __launch_bounds__(64) void k_pair(
        const float* __restrict__ p, const float* __restrict__ q,
        const float* __restrict__ we2, const float* __restrict__ be2,
        float* __restrict__ out) {
    int t = blockIdx.x;
    int bj = (int)((sqrtf(8.f * t + 1.f) - 1.f) * 0.5f);
    while ((bj + 1) * (bj + 2) / 2 <= t) ++bj;
    while (bj * (bj + 1) / 2 > t) --bj;
    int bi = t - bj * (bj + 1) / 2;
    int i0 = bi * 16, j0 = bj * 16;
    __shared__ float spi[16][132], sqi[16][132], spj[16][132], sqj[16][132];
    __shared__ float w2s[HD];
    int tid = threadIdx.x;
    for (int idx = tid; idx < 512; idx += 64) {
        int r = idx >> 5, c4 = idx & 31;
        *(float4*)&spi[r][c4 * 4] = *(const float4*)&p[(i0 + r) * HD + c4 * 4];
        *(float4*)&sqi[r][c4 * 4] = *(const float4*)&q[(i0 + r) * HD + c4 * 4];
        *(float4*)&spj[r][c4 * 4] = *(const float4*)&p[(j0 + r) * HD + c4 * 4];
        *(float4*)&sqj[r][c4 * 4] = *(const float4*)&q[(j0 + r) * HD + c4 * 4];
    }
    w2s[tid] = we2[tid];
    w2s[tid + 64] = we2[tid + 64];
    __syncthreads();
    int tx = tid & 7, ty = tid >> 3;
    float accij[2][2] = {{0.f, 0.f}, {0.f, 0.f}};
    float accji[2][2] = {{0.f, 0.f}, {0.f, 0.f}};
#pragma unroll 4
    for (int k4 = 0; k4 < 32; ++k4) {
        float4 w = *(float4*)&w2s[k4 * 4];
        float4 Pi0 = *(float4*)&spi[2 * ty + 0][k4 * 4];
        float4 Pi1 = *(float4*)&spi[2 * ty + 1][k4 * 4];
        float4 Qi0 = *(float4*)&sqi[2 * ty + 0][k4 * 4];
        float4 Qi1 = *(float4*)&sqi[2 * ty + 1][k4 * 4];
        float4 Pj0 = *(float4*)&spj[2 * tx + 0][k4 * 4];
        float4 Pj1 = *(float4*)&spj[2 * tx + 1][k4 * 4];
        float4 Qj0 = *(float4*)&sqj[2 * tx + 0][k4 * 4];
        float4 Qj1 = *(float4*)&sqj[2 * tx + 1][k4 * 4];
        accij[0][0] += rdot(Pi0, Qj0, w); accji[0][0] += rdot(Pj0, Qi0, w);
        accij[0][1] += rdot(Pi0, Qj1, w); accji[0][1] += rdot(Pj1, Qi0, w);
        accij[1][0] += rdot(Pi1, Qj0, w); accji[1][0] += rdot(Pj0, Qi1, w);
        accij[1][1] += rdot(Pi1, Qj1, w); accji[1][1] += rdot(Pj1, Qi1, w);
    }
    float bias = be2[0];
#pragma unroll
    for (int e = 0; e < 2; ++e)
#pragma unroll
        for (int f = 0; f < 2; ++f) {
            int i = i0 + 2 * ty + e, j = j0 + 2 * tx + f;
            float lij = accij[e][f] + bias, lji = accji[e][f] + bias;
            float v = 0.5f * (1.f / (1.f + __expf(-lij)) + 1.f / (1.f + __expf(-lji)));
            out[i * NN + j] = v;
            out[j * NN + i] = v;
        }
}

extern "C" void kernel_launch(void* const* d_in, const int* in_sizes, int n_in,
                              void* d_out, int out_size, void* d_ws, size_t ws_size,
                              hipStream_t stream) {
    const float* x    = (const float*)d_in[0];
    const float* adj  = (const float*)d_in[1];
    const float* w1   = (const float*)d_in[2];
    const float* w2   = (const float*)d_in[3];
    const float* temb = (const float*)d_in[4];
    const float* we1  = (const float*)d_in[5];
    const float* be1  = (const float*)d_in[6];
    const float* we2  = (const float*)d_in[7];
    const float* be2  = (const float*)d_in[8];
    const int* tptr   = (const int*)d_in[9];
    float* out        = (float*)d_out;

    float* ws   = (float*)d_ws;
    float* dinv = ws;               // 768
    float* c    = ws + 768;         // 128
    float* A    = ws + 1024;        // 768*128  t1D, later p
    float* B    = A + NN * HD;      // 768*128  t2D
    float* C    = B + NN * HD;      // 768*128  q

    k_prep  <<<257, 768, 0, stream>>>(x, adj, w1, temb, we1, be1, tptr, dinv, c, A);
    k_gcn_w <<<256, 768, 0, stream>>>(adj, dinv, A, w2, B);
    k_gcn_pq<<<256, 768, 0, stream>>>(adj, dinv, B, we1, c, A, C);
    k_pair  <<<1176, 64, 0, stream>>>(A, C, we2, be2, out);
}